// Round 2
// baseline (1247.027 us; speedup 1.0000x reference)
//
#include <hip/hip_runtime.h>
#include <stdint.h>

#define N_KERNELS 10000
#define NCHUNK 56            // >= sum_g ceil(size_g/256) worst case (<=54)
#define RNG_STEPS 160        // 64 lanes * 160 next64 = 20480 u32 draws >= 20000
#define REGSTRIDE 1216       // floats per (batch,channel) LDS region (max over K,D)

typedef unsigned __int128 u128;

// ---------------------------------------------------------------------------
// Kernel A: replicate numpy default_rng(0) -> PCG64 -> integers(0,3) x10000,
// integers(0,5) x10000 (verified passing in round 1 — unchanged).
// ---------------------------------------------------------------------------
__global__ void rng_kernel(int* __restrict__ karr, int* __restrict__ darr) {
    const u128 MULT = (((u128)0x2360ED051FC65DA4ULL) << 64) | 0x4385DF649FCCF645ULL;

    uint32_t hc = 0x43b0d7e5u;                    // INIT_A
    auto hashmix = [&hc](uint32_t v) -> uint32_t {
        v ^= hc; hc *= 0x931e8875u;               // MULT_A
        v *= hc; v ^= v >> 16; return v;
    };
    uint32_t pool[4];
    pool[0] = hashmix(0u);
    pool[1] = hashmix(0u);
    pool[2] = hashmix(0u);
    pool[3] = hashmix(0u);
    for (int s = 0; s < 4; s++)
        for (int dd = 0; dd < 4; dd++)
            if (s != dd) {
                uint32_t hv = hashmix(pool[s]);
                uint32_t rr = 0xca01f9ddu * pool[dd] - 0x4973f715u * hv;
                rr ^= rr >> 16;
                pool[dd] = rr;
            }
    uint32_t st[8];
    uint32_t hcb = 0x8b51f9ddu;                   // INIT_B
    for (int i = 0; i < 8; i++) {
        uint32_t dv = pool[i & 3];
        dv ^= hcb; hcb *= 0x58f38dedu;            // MULT_B
        dv *= hcb; dv ^= dv >> 16;
        st[i] = dv;
    }
    uint64_t w0 = (uint64_t)st[0] | ((uint64_t)st[1] << 32);
    uint64_t w1 = (uint64_t)st[2] | ((uint64_t)st[3] << 32);
    uint64_t w2 = (uint64_t)st[4] | ((uint64_t)st[5] << 32);
    uint64_t w3 = (uint64_t)st[6] | ((uint64_t)st[7] << 32);
    u128 initstate = (((u128)w0) << 64) | w1;
    u128 initseq   = (((u128)w2) << 64) | w3;

    u128 inc   = (initseq << 1) | 1;
    u128 state = 0;
    state = state * MULT + inc;
    state += initstate;
    state = state * MULT + inc;

    int lane = threadIdx.x;
    u128 Ae = 1, Ce = 0, Ab = MULT, Cb = inc;
    unsigned e = (unsigned)(lane * RNG_STEPS);
    while (e) {
        if (e & 1u) { Ae = Ab * Ae; Ce = Ab * Ce + Cb; }
        Cb = Ab * Cb + Cb;
        Ab = Ab * Ab;
        e >>= 1;
    }
    u128 s = Ae * state + Ce;

    int base = lane * (2 * RNG_STEPS);
    for (int t = 0; t < RNG_STEPS; t++) {
        s = s * MULT + inc;
        uint64_t hi = (uint64_t)(s >> 64), lo = (uint64_t)s;
        unsigned rot = (unsigned)(hi >> 58);
        uint64_t v = hi ^ lo;
        uint64_t o = (v >> rot) | (v << ((64u - rot) & 63u));
        uint32_t d0 = (uint32_t)o;
        uint32_t d1 = (uint32_t)(o >> 32);
        int i0 = base + 2 * t;
        if (i0 < 10000)       karr[i0] = (int)(((uint64_t)d0 * 3u) >> 32);
        else if (i0 < 20000)  darr[i0 - 10000] = (int)(((uint64_t)d0 * 5u) >> 32);
        int i1 = i0 + 1;
        if (i1 < 10000)       karr[i1] = (int)(((uint64_t)d1 * 3u) >> 32);
        else if (i1 < 20000)  darr[i1 - 10000] = (int)(((uint64_t)d1 * 5u) >> 32);
    }
}

// ---------------------------------------------------------------------------
// Kernel B: bucket kernels by (k,d) group; chunk table of 256-kernel chunks:
// sched[ci] = int4{ k, log2(d), list_start, valid }  (valid==0 -> dead)
// ---------------------------------------------------------------------------
__global__ void sched_kernel(const int* __restrict__ karr, const int* __restrict__ darr,
                             int* __restrict__ list, int* __restrict__ sched) {
    __shared__ int cnt[16], off[16], cur[16];
    int tid = threadIdx.x;
    if (tid < 16) cnt[tid] = 0;
    __syncthreads();
    for (int i = tid; i < N_KERNELS; i += 256)
        atomicAdd(&cnt[karr[i] * 5 + darr[i]], 1);
    __syncthreads();
    if (tid == 0) { int o = 0; for (int g = 0; g < 15; g++) { off[g] = o; o += cnt[g]; } }
    __syncthreads();
    if (tid < 16) cur[tid] = 0;
    __syncthreads();
    for (int i = tid; i < N_KERNELS; i += 256) {
        int g = karr[i] * 5 + darr[i];
        list[off[g] + atomicAdd(&cur[g], 1)] = i;
    }
    __syncthreads();
    if (tid == 0) {
        const int kv[3] = {7, 9, 11};
        int ci = 0;
        for (int g = 0; g < 15; g++) {
            int sz = cnt[g];
            for (int s = 0; s < sz; s += 256) {
                int4 e;
                e.x = kv[g / 5];
                e.y = g % 5;
                e.z = off[g] + s;
                e.w = (sz - s < 256) ? (sz - s) : 256;
                reinterpret_cast<int4*>(sched)[ci++] = e;
            }
        }
        for (; ci < NCHUNK; ci++) {
            int4 e; e.x = 0; e.y = 0; e.z = 0; e.w = 0;
            reinterpret_cast<int4*>(sched)[ci] = e;
        }
    }
}

// ---------------------------------------------------------------------------
// Kernel C: one thread = 2 kernels x 1 batch, full T range, running max+ppv.
// x de-interleaved by residue in LDS; all x reads are wave-uniform broadcasts
// via ds_read_b128 with compile-time offsets (K and D are template params).
// ---------------------------------------------------------------------------
template <int K, int D>
__device__ __forceinline__ void body(const float* __restrict__ x,
                                     const float* __restrict__ wgt,
                                     const float* __restrict__ bias,
                                     const int* __restrict__ list,
                                     int lstart, int valid,
                                     float* __restrict__ out,
                                     float* __restrict__ xs,   // [2][3][REGSTRIDE]
                                     int b0) {
    constexpr int H   = (K - 1) / 2;
    constexpr int LD2 = (D == 1 ? 0 : D == 2 ? 1 : D == 4 ? 2 : D == 8 ? 3 : 4);
    constexpr int Q   = 1024 >> LD2;                  // positions per residue
    constexpr int L4  = (Q + 2 * H + 3) & ~3;         // row pitch (16B aligned)
    constexpr int NF4 = (K + 7 + 3) / 4;              // float4 reads per channel chunk

    const int tid  = threadIdx.x;
    const int lane = tid & 63;
    const int wave = tid >> 6;
    const int bsub = wave & 1;       // which of the 2 staged batches
    const int half = wave >> 1;      // which 128-kernel half

    // zero halos/pads (zero everything: once per block, cheap)
    for (int i = tid; i < 6 * REGSTRIDE; i += 256) xs[i] = 0.f;
    __syncthreads();

    // stage 2 batches x 3 channels x 1024 floats, de-interleaved by residue
    #pragma unroll
    for (int m = 0; m < 6; m++) {
        int f4  = tid + 256 * m;          // 0..1535
        int bo  = f4 / 768;
        int rem = f4 - bo * 768;
        int c   = rem >> 8;
        int p4  = rem & 255;
        float4 xv = reinterpret_cast<const float4*>(x)[((size_t)(b0 + bo) * 3 + c) * 256 + p4];
        float* reg = xs + (bo * 3 + c) * REGSTRIDE;
        int p = p4 << 2;
        { int pp = p;     reg[(pp & (D - 1)) * L4 + H + (pp >> LD2)] = xv.x; }
        { int pp = p + 1; reg[(pp & (D - 1)) * L4 + H + (pp >> LD2)] = xv.y; }
        { int pp = p + 2; reg[(pp & (D - 1)) * L4 + H + (pp >> LD2)] = xv.z; }
        { int pp = p + 3; reg[(pp & (D - 1)) * L4 + H + (pp >> LD2)] = xv.w; }
    }

    // per-thread kernel pair (weight loads overlap the staging latency)
    int i0 = half * 128 + lane;
    int i1 = i0 + 64;
    int n0 = list[lstart + (i0 < valid ? i0 : valid - 1)];
    int n1 = list[lstart + (i1 < valid ? i1 : valid - 1)];
    float w0r[3 * K], w1r[3 * K];
    #pragma unroll
    for (int c = 0; c < 3; c++)
        #pragma unroll
        for (int j = 0; j < K; j++) {
            w0r[c * K + j] = wgt[n0 * 33 + c * 11 + j];
            w1r[c * K + j] = wgt[n1 * 33 + c * 11 + j];
        }
    float bv0 = bias[n0], bv1 = bias[n1];

    __syncthreads();

    float mx0 = -3.402823466e38f, mx1 = -3.402823466e38f;
    int   c0 = 0, c1 = 0;

    const float* reg = xs + bsub * 3 * REGSTRIDE;
    for (int r = 0; r < D; r++) {
        const float* rrow = reg + r * L4;
        for (int q0 = 0; q0 < Q; q0 += 8) {
            float acc0[8], acc1[8];
            #pragma unroll
            for (int p = 0; p < 8; p++) { acc0[p] = bv0; acc1[p] = bv1; }
            #pragma unroll
            for (int c = 0; c < 3; c++) {
                float4 xq[NF4];
                const float4* src = reinterpret_cast<const float4*>(rrow + c * REGSTRIDE + q0);
                #pragma unroll
                for (int u = 0; u < NF4; u++) xq[u] = src[u];
                const float* xv = reinterpret_cast<const float*>(&xq[0]);
                #pragma unroll
                for (int j = 0; j < K; j++) {
                    float a0 = w0r[c * K + j], a1 = w1r[c * K + j];
                    #pragma unroll
                    for (int p = 0; p < 8; p++) {
                        acc0[p] = fmaf(a0, xv[p + j], acc0[p]);
                        acc1[p] = fmaf(a1, xv[p + j], acc1[p]);
                    }
                }
            }
            #pragma unroll
            for (int p = 0; p < 8; p++) {
                mx0 = fmaxf(mx0, acc0[p]);
                mx1 = fmaxf(mx1, acc1[p]);
                c0 += acc0[p] > 0.f ? 1 : 0;
                c1 += acc1[p] > 0.f ? 1 : 0;
            }
        }
    }

    int b = b0 + bsub;
    float2* ob = reinterpret_cast<float2*>(out + (size_t)b * (2 * N_KERNELS));
    ob[n0] = make_float2(mx0, (float)c0 * (1.0f / 1024.0f));
    ob[n1] = make_float2(mx1, (float)c1 * (1.0f / 1024.0f));
}

__global__ __launch_bounds__(256, 4)
void rocket_main(const float* __restrict__ x, const float* __restrict__ wgt,
                 const float* __restrict__ bias, const int* __restrict__ list,
                 const int* __restrict__ sched, float* __restrict__ out) {
    __shared__ __align__(16) float xs[6 * REGSTRIDE];   // 28.5 KB
    int4 e = reinterpret_cast<const int4*>(sched)[blockIdx.x];
    if (e.w == 0) return;                                // dead chunk — uniform exit
    int b0 = blockIdx.y * 2;
    int kc = e.x, ld2 = e.y, lstart = e.z, valid = e.w;
    switch (kc * 8 + ld2) {
        case 7*8+0:  body<7, 1 >(x, wgt, bias, list, lstart, valid, out, xs, b0); break;
        case 7*8+1:  body<7, 2 >(x, wgt, bias, list, lstart, valid, out, xs, b0); break;
        case 7*8+2:  body<7, 4 >(x, wgt, bias, list, lstart, valid, out, xs, b0); break;
        case 7*8+3:  body<7, 8 >(x, wgt, bias, list, lstart, valid, out, xs, b0); break;
        case 7*8+4:  body<7, 16>(x, wgt, bias, list, lstart, valid, out, xs, b0); break;
        case 9*8+0:  body<9, 1 >(x, wgt, bias, list, lstart, valid, out, xs, b0); break;
        case 9*8+1:  body<9, 2 >(x, wgt, bias, list, lstart, valid, out, xs, b0); break;
        case 9*8+2:  body<9, 4 >(x, wgt, bias, list, lstart, valid, out, xs, b0); break;
        case 9*8+3:  body<9, 8 >(x, wgt, bias, list, lstart, valid, out, xs, b0); break;
        case 9*8+4:  body<9, 16>(x, wgt, bias, list, lstart, valid, out, xs, b0); break;
        case 11*8+0: body<11,1 >(x, wgt, bias, list, lstart, valid, out, xs, b0); break;
        case 11*8+1: body<11,2 >(x, wgt, bias, list, lstart, valid, out, xs, b0); break;
        case 11*8+2: body<11,4 >(x, wgt, bias, list, lstart, valid, out, xs, b0); break;
        case 11*8+3: body<11,8 >(x, wgt, bias, list, lstart, valid, out, xs, b0); break;
        default:     body<11,16>(x, wgt, bias, list, lstart, valid, out, xs, b0); break;
    }
}

extern "C" void kernel_launch(void* const* d_in, const int* in_sizes, int n_in,
                              void* d_out, int out_size, void* d_ws, size_t ws_size,
                              hipStream_t stream) {
    const float* x   = (const float*)d_in[0];
    const float* w   = (const float*)d_in[1];
    const float* b   = (const float*)d_in[2];
    float* out = (float*)d_out;

    int* wsi  = (int*)d_ws;
    int* karr = wsi;            // 10000
    int* darr = wsi + 10000;    // 10000
    int* list = wsi + 20000;    // 10000
    int* schd = wsi + 30000;    // NCHUNK*4 ints (16B aligned: 30000*4 % 16 == 0)

    hipLaunchKernelGGL(rng_kernel,   dim3(1), dim3(64),  0, stream, karr, darr);
    hipLaunchKernelGGL(sched_kernel, dim3(1), dim3(256), 0, stream, karr, darr, list, schd);
    hipLaunchKernelGGL(rocket_main,  dim3(NCHUNK, 32), dim3(256), 0, stream,
                       x, w, b, list, schd, out);
}

// Round 3
// 722.672 us; speedup vs baseline: 1.7256x; 1.7256x over previous
//
#include <hip/hip_runtime.h>
#include <stdint.h>

#define N_KERNELS 10000
#define NCHUNK 56            // >= sum_g ceil(size_g/256) worst case
#define RNG_STEPS 160        // 64 lanes * 160 next64 = 20480 u32 draws >= 20000
#define REGSTRIDE 1216       // floats per channel LDS region (max over K,D: 16*76)

typedef unsigned __int128 u128;

// ---------------------------------------------------------------------------
// Kernel A: replicate numpy default_rng(0) -> PCG64 -> integers(0,3) x10000,
// integers(0,5) x10000 (verified passing in rounds 1-2 — unchanged).
// ---------------------------------------------------------------------------
__global__ void rng_kernel(int* __restrict__ karr, int* __restrict__ darr) {
    const u128 MULT = (((u128)0x2360ED051FC65DA4ULL) << 64) | 0x4385DF649FCCF645ULL;

    uint32_t hc = 0x43b0d7e5u;                    // INIT_A
    auto hashmix = [&hc](uint32_t v) -> uint32_t {
        v ^= hc; hc *= 0x931e8875u;               // MULT_A
        v *= hc; v ^= v >> 16; return v;
    };
    uint32_t pool[4];
    pool[0] = hashmix(0u);
    pool[1] = hashmix(0u);
    pool[2] = hashmix(0u);
    pool[3] = hashmix(0u);
    for (int s = 0; s < 4; s++)
        for (int dd = 0; dd < 4; dd++)
            if (s != dd) {
                uint32_t hv = hashmix(pool[s]);
                uint32_t rr = 0xca01f9ddu * pool[dd] - 0x4973f715u * hv;
                rr ^= rr >> 16;
                pool[dd] = rr;
            }
    uint32_t st[8];
    uint32_t hcb = 0x8b51f9ddu;                   // INIT_B
    for (int i = 0; i < 8; i++) {
        uint32_t dv = pool[i & 3];
        dv ^= hcb; hcb *= 0x58f38dedu;            // MULT_B
        dv *= hcb; dv ^= dv >> 16;
        st[i] = dv;
    }
    uint64_t w0 = (uint64_t)st[0] | ((uint64_t)st[1] << 32);
    uint64_t w1 = (uint64_t)st[2] | ((uint64_t)st[3] << 32);
    uint64_t w2 = (uint64_t)st[4] | ((uint64_t)st[5] << 32);
    uint64_t w3 = (uint64_t)st[6] | ((uint64_t)st[7] << 32);
    u128 initstate = (((u128)w0) << 64) | w1;
    u128 initseq   = (((u128)w2) << 64) | w3;

    u128 inc   = (initseq << 1) | 1;
    u128 state = 0;
    state = state * MULT + inc;
    state += initstate;
    state = state * MULT + inc;

    int lane = threadIdx.x;
    u128 Ae = 1, Ce = 0, Ab = MULT, Cb = inc;
    unsigned e = (unsigned)(lane * RNG_STEPS);
    while (e) {
        if (e & 1u) { Ae = Ab * Ae; Ce = Ab * Ce + Cb; }
        Cb = Ab * Cb + Cb;
        Ab = Ab * Ab;
        e >>= 1;
    }
    u128 s = Ae * state + Ce;

    int base = lane * (2 * RNG_STEPS);
    for (int t = 0; t < RNG_STEPS; t++) {
        s = s * MULT + inc;
        uint64_t hi = (uint64_t)(s >> 64), lo = (uint64_t)s;
        unsigned rot = (unsigned)(hi >> 58);
        uint64_t v = hi ^ lo;
        uint64_t o = (v >> rot) | (v << ((64u - rot) & 63u));
        uint32_t d0 = (uint32_t)o;
        uint32_t d1 = (uint32_t)(o >> 32);
        int i0 = base + 2 * t;
        if (i0 < 10000)       karr[i0] = (int)(((uint64_t)d0 * 3u) >> 32);
        else if (i0 < 20000)  darr[i0 - 10000] = (int)(((uint64_t)d0 * 5u) >> 32);
        int i1 = i0 + 1;
        if (i1 < 10000)       karr[i1] = (int)(((uint64_t)d1 * 3u) >> 32);
        else if (i1 < 20000)  darr[i1 - 10000] = (int)(((uint64_t)d1 * 5u) >> 32);
    }
}

// ---------------------------------------------------------------------------
// Kernel B: bucket kernels by (k,d) group; chunk table of 256-kernel chunks:
// sched[ci] = int4{ k, log2(d), list_start, valid }  (valid==0 -> dead)
// ---------------------------------------------------------------------------
__global__ void sched_kernel(const int* __restrict__ karr, const int* __restrict__ darr,
                             int* __restrict__ list, int* __restrict__ sched) {
    __shared__ int cnt[16], off[16], cur[16];
    int tid = threadIdx.x;
    if (tid < 16) cnt[tid] = 0;
    __syncthreads();
    for (int i = tid; i < N_KERNELS; i += 256)
        atomicAdd(&cnt[karr[i] * 5 + darr[i]], 1);
    __syncthreads();
    if (tid == 0) { int o = 0; for (int g = 0; g < 15; g++) { off[g] = o; o += cnt[g]; } }
    __syncthreads();
    if (tid < 16) cur[tid] = 0;
    __syncthreads();
    for (int i = tid; i < N_KERNELS; i += 256) {
        int g = karr[i] * 5 + darr[i];
        list[off[g] + atomicAdd(&cur[g], 1)] = i;
    }
    __syncthreads();
    if (tid == 0) {
        const int kv[3] = {7, 9, 11};
        int ci = 0;
        for (int g = 0; g < 15; g++) {
            int sz = cnt[g];
            for (int s = 0; s < sz; s += 256) {
                int4 e;
                e.x = kv[g / 5];
                e.y = g % 5;
                e.z = off[g] + s;
                e.w = (sz - s < 256) ? (sz - s) : 256;
                reinterpret_cast<int4*>(sched)[ci++] = e;
            }
        }
        for (; ci < NCHUNK; ci++) {
            int4 e; e.x = 0; e.y = 0; e.z = 0; e.w = 0;
            reinterpret_cast<int4*>(sched)[ci] = e;
        }
    }
}

// ---------------------------------------------------------------------------
// Kernel C: one thread = ONE kernel x one batch (33 weights + 16 acc in regs,
// no spill). Block = 256 kernels x 1 batch; x de-interleaved by residue in
// LDS; all x reads are wave-uniform ds_read_b128 broadcasts, 16 outputs/iter.
// ---------------------------------------------------------------------------
template <int K, int D>
__device__ __forceinline__ void body(const float* __restrict__ x,
                                     const float* __restrict__ wgt,
                                     const float* __restrict__ bias,
                                     const int* __restrict__ list,
                                     int lstart, int valid,
                                     float* __restrict__ out,
                                     float* __restrict__ xs,   // [3][REGSTRIDE]
                                     int b) {
    constexpr int H   = (K - 1) / 2;
    constexpr int LD2 = (D == 1 ? 0 : D == 2 ? 1 : D == 4 ? 2 : D == 8 ? 3 : 4);
    constexpr int Q   = 1024 >> LD2;                  // positions per residue
    constexpr int L4  = (Q + 2 * H + 3) & ~3;         // row pitch (16B aligned)
    constexpr int NF4 = (16 + K - 1 + 3) / 4;         // float4 reads per chan/iter

    const int tid = threadIdx.x;

    // zero all (halos/pads must be 0; staging overwrites data slots)
    for (int i = tid; i < 3 * REGSTRIDE; i += 256) xs[i] = 0.f;
    __syncthreads();

    // stage 1 batch x 3 channels x 1024 floats, de-interleaved by residue
    #pragma unroll
    for (int m = 0; m < 3; m++) {
        int f4 = tid + 256 * m;           // 0..767
        int c  = f4 >> 8;
        int p4 = f4 & 255;
        float4 xv = reinterpret_cast<const float4*>(x)[((size_t)b * 3 + c) * 256 + p4];
        float* reg = xs + c * REGSTRIDE;
        int p = p4 << 2;
        { int pp = p;     reg[(pp & (D - 1)) * L4 + H + (pp >> LD2)] = xv.x; }
        { int pp = p + 1; reg[(pp & (D - 1)) * L4 + H + (pp >> LD2)] = xv.y; }
        { int pp = p + 2; reg[(pp & (D - 1)) * L4 + H + (pp >> LD2)] = xv.z; }
        { int pp = p + 3; reg[(pp & (D - 1)) * L4 + H + (pp >> LD2)] = xv.w; }
    }

    // this thread's kernel (global loads overlap staging latency)
    int i0 = tid < valid ? tid : valid - 1;
    int n  = list[lstart + i0];
    float wr[3 * K];
    #pragma unroll
    for (int c = 0; c < 3; c++)
        #pragma unroll
        for (int j = 0; j < K; j++)
            wr[c * K + j] = wgt[n * 33 + c * 11 + j];
    float bv = bias[n];

    __syncthreads();

    float mx = -3.402823466e38f;
    int   cp = 0;

    #pragma unroll 1
    for (int r = 0; r < D; r++) {
        const float* rrow = xs + r * L4;
        #pragma unroll 1
        for (int q0 = 0; q0 < Q; q0 += 16) {
            float acc[16];
            #pragma unroll
            for (int p = 0; p < 16; p++) acc[p] = bv;
            #pragma unroll
            for (int c = 0; c < 3; c++) {
                float4 xq[NF4];
                const float4* src = reinterpret_cast<const float4*>(rrow + c * REGSTRIDE + q0);
                #pragma unroll
                for (int u = 0; u < NF4; u++) xq[u] = src[u];
                const float* xv = reinterpret_cast<const float*>(&xq[0]);
                #pragma unroll
                for (int j = 0; j < K; j++) {
                    float a = wr[c * K + j];
                    #pragma unroll
                    for (int p = 0; p < 16; p++)
                        acc[p] = fmaf(a, xv[p + j], acc[p]);
                }
            }
            #pragma unroll
            for (int p = 0; p < 16; p++) {
                mx = fmaxf(mx, acc[p]);
                cp += acc[p] > 0.f ? 1 : 0;
            }
        }
    }

    float2* ob = reinterpret_cast<float2*>(out + (size_t)b * (2 * N_KERNELS));
    ob[n] = make_float2(mx, (float)cp * (1.0f / 1024.0f));
}

__global__ __launch_bounds__(256, 2)
void rocket_main(const float* __restrict__ x, const float* __restrict__ wgt,
                 const float* __restrict__ bias, const int* __restrict__ list,
                 const int* __restrict__ sched, float* __restrict__ out) {
    __shared__ __align__(16) float xs[3 * REGSTRIDE];   // 14.6 KB
    int4 e = reinterpret_cast<const int4*>(sched)[blockIdx.x];
    if (e.w == 0) return;                                // dead chunk — uniform exit
    int b = blockIdx.y;
    int kc = e.x, ld2 = e.y, lstart = e.z, valid = e.w;
    switch (kc * 8 + ld2) {
        case 7*8+0:  body<7, 1 >(x, wgt, bias, list, lstart, valid, out, xs, b); break;
        case 7*8+1:  body<7, 2 >(x, wgt, bias, list, lstart, valid, out, xs, b); break;
        case 7*8+2:  body<7, 4 >(x, wgt, bias, list, lstart, valid, out, xs, b); break;
        case 7*8+3:  body<7, 8 >(x, wgt, bias, list, lstart, valid, out, xs, b); break;
        case 7*8+4:  body<7, 16>(x, wgt, bias, list, lstart, valid, out, xs, b); break;
        case 9*8+0:  body<9, 1 >(x, wgt, bias, list, lstart, valid, out, xs, b); break;
        case 9*8+1:  body<9, 2 >(x, wgt, bias, list, lstart, valid, out, xs, b); break;
        case 9*8+2:  body<9, 4 >(x, wgt, bias, list, lstart, valid, out, xs, b); break;
        case 9*8+3:  body<9, 8 >(x, wgt, bias, list, lstart, valid, out, xs, b); break;
        case 9*8+4:  body<9, 16>(x, wgt, bias, list, lstart, valid, out, xs, b); break;
        case 11*8+0: body<11,1 >(x, wgt, bias, list, lstart, valid, out, xs, b); break;
        case 11*8+1: body<11,2 >(x, wgt, bias, list, lstart, valid, out, xs, b); break;
        case 11*8+2: body<11,4 >(x, wgt, bias, list, lstart, valid, out, xs, b); break;
        case 11*8+3: body<11,8 >(x, wgt, bias, list, lstart, valid, out, xs, b); break;
        default:     body<11,16>(x, wgt, bias, list, lstart, valid, out, xs, b); break;
    }
}

extern "C" void kernel_launch(void* const* d_in, const int* in_sizes, int n_in,
                              void* d_out, int out_size, void* d_ws, size_t ws_size,
                              hipStream_t stream) {
    const float* x   = (const float*)d_in[0];
    const float* w   = (const float*)d_in[1];
    const float* b   = (const float*)d_in[2];
    float* out = (float*)d_out;

    int* wsi  = (int*)d_ws;
    int* karr = wsi;            // 10000
    int* darr = wsi + 10000;    // 10000
    int* list = wsi + 20000;    // 10000
    int* schd = wsi + 30000;    // NCHUNK*4 ints (16B aligned)

    hipLaunchKernelGGL(rng_kernel,   dim3(1), dim3(64),  0, stream, karr, darr);
    hipLaunchKernelGGL(sched_kernel, dim3(1), dim3(256), 0, stream, karr, darr, list, schd);
    hipLaunchKernelGGL(rocket_main,  dim3(NCHUNK, 64), dim3(256), 0, stream,
                       x, w, b, list, schd, out);
}

// Round 6
// 285.070 us; speedup vs baseline: 4.3745x; 2.5351x over previous
//
#include <hip/hip_runtime.h>
#include <stdint.h>

#define N_KERNELS 10000
#define NCHUNK 56            // >= sum_g ceil(size_g/256) worst case
#define RNG_STEPS 160        // 64 lanes * 160 next64 = 20480 u32 draws >= 20000
#define CH_ALLOC 1312        // shorts per (copy,channel); mult of 8
#define PP_STRIDE (3 * CH_ALLOC)

typedef unsigned __int128 u128;
typedef __attribute__((ext_vector_type(8)))  short short8;
typedef __attribute__((ext_vector_type(16))) float floatx16;

// ---------------------------------------------------------------------------
// Kernel A: replicate numpy default_rng(0) -> PCG64 -> integers(0,3) x10000,
// integers(0,5) x10000 (verified passing in rounds 1-3 — unchanged).
// ---------------------------------------------------------------------------
__global__ void rng_kernel(int* __restrict__ karr, int* __restrict__ darr) {
    const u128 MULT = (((u128)0x2360ED051FC65DA4ULL) << 64) | 0x4385DF649FCCF645ULL;

    uint32_t hc = 0x43b0d7e5u;                    // INIT_A
    auto hashmix = [&hc](uint32_t v) -> uint32_t {
        v ^= hc; hc *= 0x931e8875u;               // MULT_A
        v *= hc; v ^= v >> 16; return v;
    };
    uint32_t pool[4];
    pool[0] = hashmix(0u);
    pool[1] = hashmix(0u);
    pool[2] = hashmix(0u);
    pool[3] = hashmix(0u);
    for (int s = 0; s < 4; s++)
        for (int dd = 0; dd < 4; dd++)
            if (s != dd) {
                uint32_t hv = hashmix(pool[s]);
                uint32_t rr = 0xca01f9ddu * pool[dd] - 0x4973f715u * hv;
                rr ^= rr >> 16;
                pool[dd] = rr;
            }
    uint32_t st[8];
    uint32_t hcb = 0x8b51f9ddu;                   // INIT_B
    for (int i = 0; i < 8; i++) {
        uint32_t dv = pool[i & 3];
        dv ^= hcb; hcb *= 0x58f38dedu;            // MULT_B
        dv *= hcb; dv ^= dv >> 16;
        st[i] = dv;
    }
    uint64_t w0 = (uint64_t)st[0] | ((uint64_t)st[1] << 32);
    uint64_t w1 = (uint64_t)st[2] | ((uint64_t)st[3] << 32);
    uint64_t w2 = (uint64_t)st[4] | ((uint64_t)st[5] << 32);
    uint64_t w3 = (uint64_t)st[6] | ((uint64_t)st[7] << 32);
    u128 initstate = (((u128)w0) << 64) | w1;
    u128 initseq   = (((u128)w2) << 64) | w3;

    u128 inc   = (initseq << 1) | 1;
    u128 state = 0;
    state = state * MULT + inc;
    state += initstate;
    state = state * MULT + inc;

    int lane = threadIdx.x;
    u128 Ae = 1, Ce = 0, Ab = MULT, Cb = inc;
    unsigned e = (unsigned)(lane * RNG_STEPS);
    while (e) {
        if (e & 1u) { Ae = Ab * Ae; Ce = Ab * Ce + Cb; }
        Cb = Ab * Cb + Cb;
        Ab = Ab * Ab;
        e >>= 1;
    }
    u128 s = Ae * state + Ce;

    int base = lane * (2 * RNG_STEPS);
    for (int t = 0; t < RNG_STEPS; t++) {
        s = s * MULT + inc;
        uint64_t hi = (uint64_t)(s >> 64), lo = (uint64_t)s;
        unsigned rot = (unsigned)(hi >> 58);
        uint64_t v = hi ^ lo;
        uint64_t o = (v >> rot) | (v << ((64u - rot) & 63u));
        uint32_t d0 = (uint32_t)o;
        uint32_t d1 = (uint32_t)(o >> 32);
        int i0 = base + 2 * t;
        if (i0 < 10000)       karr[i0] = (int)(((uint64_t)d0 * 3u) >> 32);
        else if (i0 < 20000)  darr[i0 - 10000] = (int)(((uint64_t)d0 * 5u) >> 32);
        int i1 = i0 + 1;
        if (i1 < 10000)       karr[i1] = (int)(((uint64_t)d1 * 3u) >> 32);
        else if (i1 < 20000)  darr[i1 - 10000] = (int)(((uint64_t)d1 * 5u) >> 32);
    }
}

// ---------------------------------------------------------------------------
// Kernel B: bucket kernels by (k,d) group; chunk table of 256-kernel chunks:
// sched[ci] = int4{ k, log2(d), list_start, valid }  (valid==0 -> dead)
// ---------------------------------------------------------------------------
__global__ void sched_kernel(const int* __restrict__ karr, const int* __restrict__ darr,
                             int* __restrict__ list, int* __restrict__ sched) {
    __shared__ int cnt[16], off[16], cur[16];
    int tid = threadIdx.x;
    if (tid < 16) cnt[tid] = 0;
    __syncthreads();
    for (int i = tid; i < N_KERNELS; i += 256)
        atomicAdd(&cnt[karr[i] * 5 + darr[i]], 1);
    __syncthreads();
    if (tid == 0) { int o = 0; for (int g = 0; g < 15; g++) { off[g] = o; o += cnt[g]; } }
    __syncthreads();
    if (tid < 16) cur[tid] = 0;
    __syncthreads();
    for (int i = tid; i < N_KERNELS; i += 256) {
        int g = karr[i] * 5 + darr[i];
        list[off[g] + atomicAdd(&cur[g], 1)] = i;
    }
    __syncthreads();
    if (tid == 0) {
        const int kv[3] = {7, 9, 11};
        int ci = 0;
        for (int g = 0; g < 15; g++) {
            int sz = cnt[g];
            for (int s = 0; s < sz; s += 256) {
                int4 e;
                e.x = kv[g / 5];
                e.y = g % 5;
                e.z = off[g] + s;
                e.w = (sz - s < 256) ? (sz - s) : 256;
                reinterpret_cast<int4*>(sched)[ci++] = e;
            }
        }
        for (; ci < NCHUNK; ci++) {
            int4 e; e.x = 0; e.y = 0; e.z = 0; e.w = 0;
            reinterpret_cast<int4*>(sched)[ci] = e;
        }
    }
}

// ---------------------------------------------------------------------------
// Kernel C: bf16 MFMA Toeplitz GEMM. One block = 256 kernels (4 waves x 64)
// x 1 batch. x is de-interleaved (residue-major) bf16 in LDS, replicated at
// 8 element-phases so every A-fragment is one ALIGNED ds_read_b128 (phase
// chosen PER LANE: pp=F&7, e=(F&~7)+jbase).
// R6 fix: for D>=8, rows now stride 4 (D=8, 4 sub-phases) / 2 (D=16, 2
// sub-phases) so every C row is a REAL output position (q=p+RS*m in [0,Q)
// bijective). R5 covered inter-residue gap rows whose windows reach back
// into valid data -> nonzero partial convs polluted the max (absmax 6.9).
// No masking needed anywhere now; exact 1024 positions per (kernel,batch).
// ---------------------------------------------------------------------------
__device__ __forceinline__ uint16_t f32_to_bf16(float v) {
    uint32_t u = __builtin_bit_cast(uint32_t, v);
    return (uint16_t)((u + 0x7FFFu + ((u >> 16) & 1u)) >> 16);
}

template <int K, int D>
__device__ __forceinline__ void body(const float* __restrict__ x,
                                     const float* __restrict__ wgt,
                                     const float* __restrict__ bias,
                                     const int* __restrict__ list,
                                     int lstart, int valid,
                                     float* __restrict__ out,
                                     short* __restrict__ xs,   // [8][3][CH_ALLOC]
                                     int b) {
    constexpr int H   = (K - 1) / 2;
    constexpr int Q   = 1024 / D;
    constexpr int S   = Q + 16;                    // residue slot stride (gap 16)
    constexpr int RS  = (D <= 4) ? 8 : (D == 8 ? 4 : 2);   // row stride (positions)
    constexpr int PH  = RS;                        // sub-phases per range
    constexpr int NRG = (D <= 4) ? 4 : D;          // ranges
    constexpr int RPERRES = (D <= 4) ? (4 / D) : 1;

    const int tid   = threadIdx.x;
    const int lane  = tid & 63;
    const int wave  = tid >> 6;
    const int jbase = (lane >> 5) * 8;             // k-half offset for A and B frags

    // ---- stage: write all 8 phase-copies of the padded bf16 signal --------
    // rep[pp][c][e] = sig_c[e+pp]; sig mem layout: [8 front | r*S + q | ...],
    // value at mempos m: y=m-8, r=y/S, q=y%S -> x[c, r+D*q] if r<D && q<Q else 0.
    for (int idx = tid; idx < 3 * (CH_ALLOC + 8); idx += 256) {
        int c = idx / (CH_ALLOC + 8);
        int P = idx - c * (CH_ALLOC + 8);
        float v = 0.f;
        int y = P - 8;
        if (y >= 0) {
            int r = y / S;
            int q = y - r * S;
            if (r < D && q < Q) v = x[((size_t)b * 3 + c) * 1024 + r + D * q];
        }
        short hv = (short)f32_to_bf16(v);
        #pragma unroll
        for (int pp = 0; pp < 8; ++pp) {
            int e = P - pp;
            if (e >= 0 && e < CH_ALLOC)
                xs[pp * PP_STRIDE + c * CH_ALLOC + e] = hv;
        }
    }

    // ---- per-lane B fragments (weights, hi/lo split), overlap staging -----
    int i0 = wave * 64 + (lane & 31);
    int i1 = i0 + 32;
    int n0 = list[lstart + (i0 < valid ? i0 : valid - 1)];
    int n1 = list[lstart + (i1 < valid ? i1 : valid - 1)];
    short8 whi[2][3], wlo[2][3];
    #pragma unroll
    for (int t2 = 0; t2 < 2; ++t2) {
        int n = t2 ? n1 : n0;
        #pragma unroll
        for (int c = 0; c < 3; ++c) {
            #pragma unroll
            for (int u = 0; u < 8; ++u) {
                int j = jbase + u;
                float wv = (j < 11) ? wgt[n * 33 + c * 11 + j] : 0.f;
                uint16_t h = f32_to_bf16(wv);
                float hf = __builtin_bit_cast(float, (uint32_t)h << 16);
                uint16_t l = f32_to_bf16(wv - hf);
                whi[t2][c][u] = (short)h;
                wlo[t2][c][u] = (short)l;
            }
        }
    }
    float negb0 = -bias[n0], negb1 = -bias[n1];

    __syncthreads();

    // ---- main loop: NRG ranges x PH sub-phases, no further barriers -------
    float mx0 = -3.402823466e38f, mx1 = -3.402823466e38f;
    int cnt0 = 0, cnt1 = 0;
    const int m31 = lane & 31;                     // A row / C-D column index

    #pragma unroll 1
    for (int ri = 0; ri < NRG; ++ri) {
        const int q0 = (D <= 4) ? (8 + (ri / RPERRES) * S + (ri % RPERRES) * 256)
                                : (8 + ri * S);
        #pragma unroll 1
        for (int p = 0; p < PH; ++p) {
            // row m covers position q0-8 + p + RS*m (all valid by construction)
            const int F  = q0 + p - H + RS * m31;  // window start (array index)
            const int pp = F & 7;                  // per-lane phase copy
            const int e  = (F & ~7) + jbase;       // 16B-aligned element offset
            const short* src = xs + pp * PP_STRIDE + e;
            short8 a0 = *reinterpret_cast<const short8*>(src);
            short8 a1 = *reinterpret_cast<const short8*>(src + CH_ALLOC);
            short8 a2 = *reinterpret_cast<const short8*>(src + 2 * CH_ALLOC);
            floatx16 C0, C1;
            #pragma unroll
            for (int i = 0; i < 16; ++i) { C0[i] = 0.f; C1[i] = 0.f; }
            C0 = __builtin_amdgcn_mfma_f32_32x32x16_bf16(a0, whi[0][0], C0, 0, 0, 0);
            C1 = __builtin_amdgcn_mfma_f32_32x32x16_bf16(a0, whi[1][0], C1, 0, 0, 0);
            C0 = __builtin_amdgcn_mfma_f32_32x32x16_bf16(a0, wlo[0][0], C0, 0, 0, 0);
            C1 = __builtin_amdgcn_mfma_f32_32x32x16_bf16(a0, wlo[1][0], C1, 0, 0, 0);
            C0 = __builtin_amdgcn_mfma_f32_32x32x16_bf16(a1, whi[0][1], C0, 0, 0, 0);
            C1 = __builtin_amdgcn_mfma_f32_32x32x16_bf16(a1, whi[1][1], C1, 0, 0, 0);
            C0 = __builtin_amdgcn_mfma_f32_32x32x16_bf16(a1, wlo[0][1], C0, 0, 0, 0);
            C1 = __builtin_amdgcn_mfma_f32_32x32x16_bf16(a1, wlo[1][1], C1, 0, 0, 0);
            C0 = __builtin_amdgcn_mfma_f32_32x32x16_bf16(a2, whi[0][2], C0, 0, 0, 0);
            C1 = __builtin_amdgcn_mfma_f32_32x32x16_bf16(a2, whi[1][2], C1, 0, 0, 0);
            C0 = __builtin_amdgcn_mfma_f32_32x32x16_bf16(a2, wlo[0][2], C0, 0, 0, 0);
            C1 = __builtin_amdgcn_mfma_f32_32x32x16_bf16(a2, wlo[1][2], C1, 0, 0, 0);
            #pragma unroll
            for (int i = 0; i < 16; ++i) {
                float v0 = C0[i], v1 = C1[i];
                mx0 = fmaxf(mx0, v0);
                mx1 = fmaxf(mx1, v1);
                cnt0 += (v0 > negb0) ? 1 : 0;
                cnt1 += (v1 > negb1) ? 1 : 0;
            }
        }
    }

    // ---- merge complementary row halves across the (L, L^32) lane pair ----
    mx0  = fmaxf(mx0, __shfl_xor(mx0, 32));
    mx1  = fmaxf(mx1, __shfl_xor(mx1, 32));
    cnt0 += __shfl_xor(cnt0, 32);
    cnt1 += __shfl_xor(cnt1, 32);

    if (lane < 32) {
        float2* ob = reinterpret_cast<float2*>(out + (size_t)b * (2 * N_KERNELS));
        ob[n0] = make_float2(mx0 - negb0, (float)cnt0 * (1.0f / 1024.0f));
        ob[n1] = make_float2(mx1 - negb1, (float)cnt1 * (1.0f / 1024.0f));
    }
}

__global__ __launch_bounds__(256, 2)
void rocket_main(const float* __restrict__ x, const float* __restrict__ wgt,
                 const float* __restrict__ bias, const int* __restrict__ list,
                 const int* __restrict__ sched, float* __restrict__ out) {
    __shared__ __align__(16) short xs[8 * PP_STRIDE];   // 61.5 KB
    int4 e = reinterpret_cast<const int4*>(sched)[blockIdx.x];
    if (e.w == 0) return;                                // dead chunk — uniform exit
    int b = blockIdx.y;
    int kc = e.x, ld2 = e.y, lstart = e.z, valid = e.w;
    switch (kc * 8 + ld2) {
        case 7*8+0:  body<7, 1 >(x, wgt, bias, list, lstart, valid, out, xs, b); break;
        case 7*8+1:  body<7, 2 >(x, wgt, bias, list, lstart, valid, out, xs, b); break;
        case 7*8+2:  body<7, 4 >(x, wgt, bias, list, lstart, valid, out, xs, b); break;
        case 7*8+3:  body<7, 8 >(x, wgt, bias, list, lstart, valid, out, xs, b); break;
        case 7*8+4:  body<7, 16>(x, wgt, bias, list, lstart, valid, out, xs, b); break;
        case 9*8+0:  body<9, 1 >(x, wgt, bias, list, lstart, valid, out, xs, b); break;
        case 9*8+1:  body<9, 2 >(x, wgt, bias, list, lstart, valid, out, xs, b); break;
        case 9*8+2:  body<9, 4 >(x, wgt, bias, list, lstart, valid, out, xs, b); break;
        case 9*8+3:  body<9, 8 >(x, wgt, bias, list, lstart, valid, out, xs, b); break;
        case 9*8+4:  body<9, 16>(x, wgt, bias, list, lstart, valid, out, xs, b); break;
        case 11*8+0: body<11,1 >(x, wgt, bias, list, lstart, valid, out, xs, b); break;
        case 11*8+1: body<11,2 >(x, wgt, bias, list, lstart, valid, out, xs, b); break;
        case 11*8+2: body<11,4 >(x, wgt, bias, list, lstart, valid, out, xs, b); break;
        case 11*8+3: body<11,8 >(x, wgt, bias, list, lstart, valid, out, xs, b); break;
        default:     body<11,16>(x, wgt, bias, list, lstart, valid, out, xs, b); break;
    }
}

extern "C" void kernel_launch(void* const* d_in, const int* in_sizes, int n_in,
                              void* d_out, int out_size, void* d_ws, size_t ws_size,
                              hipStream_t stream) {
    const float* x   = (const float*)d_in[0];
    const float* w   = (const float*)d_in[1];
    const float* b   = (const float*)d_in[2];
    float* out = (float*)d_out;

    int* wsi  = (int*)d_ws;
    int* karr = wsi;            // 10000
    int* darr = wsi + 10000;    // 10000
    int* list = wsi + 20000;    // 10000
    int* schd = wsi + 30000;    // NCHUNK*4 ints (16B aligned)

    hipLaunchKernelGGL(rng_kernel,   dim3(1), dim3(64),  0, stream, karr, darr);
    hipLaunchKernelGGL(sched_kernel, dim3(1), dim3(256), 0, stream, karr, darr, list, schd);
    hipLaunchKernelGGL(rocket_main,  dim3(NCHUNK, 64), dim3(256), 0, stream,
                       x, w, b, list, schd, out);
}

// Round 7
// 262.184 us; speedup vs baseline: 4.7563x; 1.0873x over previous
//
#include <hip/hip_runtime.h>
#include <stdint.h>

#define N_KERNELS 10000
#define NCHUNK 56            // >= sum_g ceil(size_g/256) worst case
#define RNG_STEPS 40         // 256 lanes * 40 next64 = 20480 u32 draws >= 20000
#define CH_ALLOC 1312        // shorts per (copy,channel); mult of 8
#define PP_STRIDE (3 * CH_ALLOC)

typedef unsigned __int128 u128;
typedef __attribute__((ext_vector_type(8)))  short short8;
typedef __attribute__((ext_vector_type(16))) float floatx16;

// ---------------------------------------------------------------------------
// Kernel A+B merged: (1) replicate numpy default_rng(0) -> PCG64 ->
// integers(0,3) x10000, integers(0,5) x10000 (RNG verified R1-R6; now 256
// lanes x 40 steps instead of 64 x 160 -> 4x shorter serial tail).
// (2) bucket kernels by (k,d) group; chunk table sched[ci] =
// int4{ k, log2(d), list_start, valid } (valid==0 -> dead).
// Single block: global writes ordered by __syncthreads within the block.
// ---------------------------------------------------------------------------
__global__ void setup_kernel(int* __restrict__ karr, int* __restrict__ darr,
                             int* __restrict__ list, int* __restrict__ sched) {
    const u128 MULT = (((u128)0x2360ED051FC65DA4ULL) << 64) | 0x4385DF649FCCF645ULL;
    const int tid = threadIdx.x;

    // --- SeedSequence(0) pool mixing (all lanes identical) ---
    uint32_t hc = 0x43b0d7e5u;                    // INIT_A
    auto hashmix = [&hc](uint32_t v) -> uint32_t {
        v ^= hc; hc *= 0x931e8875u;               // MULT_A
        v *= hc; v ^= v >> 16; return v;
    };
    uint32_t pool[4];
    pool[0] = hashmix(0u);
    pool[1] = hashmix(0u);
    pool[2] = hashmix(0u);
    pool[3] = hashmix(0u);
    for (int s = 0; s < 4; s++)
        for (int dd = 0; dd < 4; dd++)
            if (s != dd) {
                uint32_t hv = hashmix(pool[s]);
                uint32_t rr = 0xca01f9ddu * pool[dd] - 0x4973f715u * hv;
                rr ^= rr >> 16;
                pool[dd] = rr;
            }
    uint32_t st[8];
    uint32_t hcb = 0x8b51f9ddu;                   // INIT_B
    for (int i = 0; i < 8; i++) {
        uint32_t dv = pool[i & 3];
        dv ^= hcb; hcb *= 0x58f38dedu;            // MULT_B
        dv *= hcb; dv ^= dv >> 16;
        st[i] = dv;
    }
    uint64_t w0 = (uint64_t)st[0] | ((uint64_t)st[1] << 32);
    uint64_t w1 = (uint64_t)st[2] | ((uint64_t)st[3] << 32);
    uint64_t w2 = (uint64_t)st[4] | ((uint64_t)st[5] << 32);
    uint64_t w3 = (uint64_t)st[6] | ((uint64_t)st[7] << 32);
    u128 initstate = (((u128)w0) << 64) | w1;
    u128 initseq   = (((u128)w2) << 64) | w3;

    u128 inc   = (initseq << 1) | 1;
    u128 state = 0;
    state = state * MULT + inc;
    state += initstate;
    state = state * MULT + inc;

    // --- per-lane jump-ahead by tid*RNG_STEPS steps ---
    u128 Ae = 1, Ce = 0, Ab = MULT, Cb = inc;
    unsigned e = (unsigned)(tid * RNG_STEPS);
    while (e) {
        if (e & 1u) { Ae = Ab * Ae; Ce = Ab * Ce + Cb; }
        Cb = Ab * Cb + Cb;
        Ab = Ab * Ab;
        e >>= 1;
    }
    u128 s = Ae * state + Ce;

    int base = tid * (2 * RNG_STEPS);
    for (int t = 0; t < RNG_STEPS; t++) {
        s = s * MULT + inc;
        uint64_t hi = (uint64_t)(s >> 64), lo = (uint64_t)s;
        unsigned rot = (unsigned)(hi >> 58);
        uint64_t v = hi ^ lo;
        uint64_t o = (v >> rot) | (v << ((64u - rot) & 63u));
        uint32_t d0 = (uint32_t)o;
        uint32_t d1 = (uint32_t)(o >> 32);
        int i0 = base + 2 * t;
        if (i0 < 10000)       karr[i0] = (int)(((uint64_t)d0 * 3u) >> 32);
        else if (i0 < 20000)  darr[i0 - 10000] = (int)(((uint64_t)d0 * 5u) >> 32);
        int i1 = i0 + 1;
        if (i1 < 10000)       karr[i1] = (int)(((uint64_t)d1 * 3u) >> 32);
        else if (i1 < 20000)  darr[i1 - 10000] = (int)(((uint64_t)d1 * 5u) >> 32);
    }

    __syncthreads();   // karr/darr visible to the whole (single) block

    // --- sched phase ---
    __shared__ int cnt[16], off[16], cur[16];
    if (tid < 16) cnt[tid] = 0;
    __syncthreads();
    for (int i = tid; i < N_KERNELS; i += 256)
        atomicAdd(&cnt[karr[i] * 5 + darr[i]], 1);
    __syncthreads();
    if (tid == 0) { int o = 0; for (int g = 0; g < 15; g++) { off[g] = o; o += cnt[g]; } }
    __syncthreads();
    if (tid < 16) cur[tid] = 0;
    __syncthreads();
    for (int i = tid; i < N_KERNELS; i += 256) {
        int g = karr[i] * 5 + darr[i];
        list[off[g] + atomicAdd(&cur[g], 1)] = i;
    }
    __syncthreads();
    if (tid == 0) {
        const int kv[3] = {7, 9, 11};
        int ci = 0;
        for (int g = 0; g < 15; g++) {
            int sz = cnt[g];
            for (int s2 = 0; s2 < sz; s2 += 256) {
                int4 e2;
                e2.x = kv[g / 5];
                e2.y = g % 5;
                e2.z = off[g] + s2;
                e2.w = (sz - s2 < 256) ? (sz - s2) : 256;
                reinterpret_cast<int4*>(sched)[ci++] = e2;
            }
        }
        for (; ci < NCHUNK; ci++) {
            int4 e2; e2.x = 0; e2.y = 0; e2.z = 0; e2.w = 0;
            reinterpret_cast<int4*>(sched)[ci] = e2;
        }
    }
}

// ---------------------------------------------------------------------------
// Kernel C: bf16 MFMA Toeplitz GEMM (R6 structure, verified correct).
// R7 perf changes only: sub-phase loop unrolled x2 (independent frag loads,
// C tiles, epilogues -> ILP at 2 waves/SIMD); epilogue max via v_max3-
// fusable triples (4-deep tree) and count split into 2 carry chains.
// ---------------------------------------------------------------------------
__device__ __forceinline__ uint16_t f32_to_bf16(float v) {
    uint32_t u = __builtin_bit_cast(uint32_t, v);
    return (uint16_t)((u + 0x7FFFu + ((u >> 16) & 1u)) >> 16);
}

__device__ __forceinline__ void stat16(const floatx16& C, float nb,
                                       float& mx, int& cA, int& cB) {
    float g0 = fmaxf(fmaxf(C[0],  C[1]),  C[2]);
    float g1 = fmaxf(fmaxf(C[3],  C[4]),  C[5]);
    float g2 = fmaxf(fmaxf(C[6],  C[7]),  C[8]);
    float g3 = fmaxf(fmaxf(C[9],  C[10]), C[11]);
    float g4 = fmaxf(fmaxf(C[12], C[13]), C[14]);
    float h0 = fmaxf(fmaxf(g0, g1), g2);
    float h1 = fmaxf(fmaxf(g3, g4), C[15]);
    mx = fmaxf(mx, fmaxf(h0, h1));
    #pragma unroll
    for (int i = 0; i < 16; i += 2) {
        cA += (C[i]     > nb) ? 1 : 0;
        cB += (C[i + 1] > nb) ? 1 : 0;
    }
}

template <int K, int D>
__device__ __forceinline__ void body(const float* __restrict__ x,
                                     const float* __restrict__ wgt,
                                     const float* __restrict__ bias,
                                     const int* __restrict__ list,
                                     int lstart, int valid,
                                     float* __restrict__ out,
                                     short* __restrict__ xs,   // [8][3][CH_ALLOC]
                                     int b) {
    constexpr int H   = (K - 1) / 2;
    constexpr int Q   = 1024 / D;
    constexpr int S   = Q + 16;                    // residue slot stride (gap 16)
    constexpr int RS  = (D <= 4) ? 8 : (D == 8 ? 4 : 2);   // row stride (positions)
    constexpr int PH  = RS;                        // sub-phases per range (even)
    constexpr int NRG = (D <= 4) ? 4 : D;          // ranges
    constexpr int RPERRES = (D <= 4) ? (4 / D) : 1;

    const int tid   = threadIdx.x;
    const int lane  = tid & 63;
    const int wave  = tid >> 6;
    const int jbase = (lane >> 5) * 8;             // k-half offset for A and B frags

    // ---- stage: write all 8 phase-copies of the padded bf16 signal --------
    for (int idx = tid; idx < 3 * (CH_ALLOC + 8); idx += 256) {
        int c = idx / (CH_ALLOC + 8);
        int P = idx - c * (CH_ALLOC + 8);
        float v = 0.f;
        int y = P - 8;
        if (y >= 0) {
            int r = y / S;
            int q = y - r * S;
            if (r < D && q < Q) v = x[((size_t)b * 3 + c) * 1024 + r + D * q];
        }
        short hv = (short)f32_to_bf16(v);
        #pragma unroll
        for (int pp = 0; pp < 8; ++pp) {
            int e = P - pp;
            if (e >= 0 && e < CH_ALLOC)
                xs[pp * PP_STRIDE + c * CH_ALLOC + e] = hv;
        }
    }

    // ---- per-lane B fragments (weights, hi/lo split), overlap staging -----
    int i0 = wave * 64 + (lane & 31);
    int i1 = i0 + 32;
    int n0 = list[lstart + (i0 < valid ? i0 : valid - 1)];
    int n1 = list[lstart + (i1 < valid ? i1 : valid - 1)];
    short8 whi[2][3], wlo[2][3];
    #pragma unroll
    for (int t2 = 0; t2 < 2; ++t2) {
        int n = t2 ? n1 : n0;
        #pragma unroll
        for (int c = 0; c < 3; ++c) {
            #pragma unroll
            for (int u = 0; u < 8; ++u) {
                int j = jbase + u;
                float wv = (j < 11) ? wgt[n * 33 + c * 11 + j] : 0.f;
                uint16_t h = f32_to_bf16(wv);
                float hf = __builtin_bit_cast(float, (uint32_t)h << 16);
                uint16_t l = f32_to_bf16(wv - hf);
                whi[t2][c][u] = (short)h;
                wlo[t2][c][u] = (short)l;
            }
        }
    }
    float negb0 = -bias[n0], negb1 = -bias[n1];

    __syncthreads();

    // ---- main loop: NRG ranges x PH sub-phases (x2 unroll), no barriers ---
    float mx0 = -3.402823466e38f, mx1 = -3.402823466e38f;
    int c0A = 0, c0B = 0, c1A = 0, c1B = 0;
    const int m31 = lane & 31;                     // A row / C-D column index

    #pragma unroll 1
    for (int ri = 0; ri < NRG; ++ri) {
        const int q0 = (D <= 4) ? (8 + (ri / RPERRES) * S + (ri % RPERRES) * 256)
                                : (8 + ri * S);
        #pragma unroll 1
        for (int p = 0; p < PH; p += 2) {
            // ---- iteration X (sub-phase p) ----
            const int FX  = q0 + p - H + RS * m31;
            const int ppX = FX & 7;
            const int eX  = (FX & ~7) + jbase;
            const short* srcX = xs + ppX * PP_STRIDE + eX;
            short8 xa0 = *reinterpret_cast<const short8*>(srcX);
            short8 xa1 = *reinterpret_cast<const short8*>(srcX + CH_ALLOC);
            short8 xa2 = *reinterpret_cast<const short8*>(srcX + 2 * CH_ALLOC);
            // ---- iteration Y (sub-phase p+1) ----
            const int FY  = FX + 1;
            const int ppY = FY & 7;
            const int eY  = (FY & ~7) + jbase;
            const short* srcY = xs + ppY * PP_STRIDE + eY;
            short8 ya0 = *reinterpret_cast<const short8*>(srcY);
            short8 ya1 = *reinterpret_cast<const short8*>(srcY + CH_ALLOC);
            short8 ya2 = *reinterpret_cast<const short8*>(srcY + 2 * CH_ALLOC);

            floatx16 CX0, CX1, CY0, CY1;
            #pragma unroll
            for (int i = 0; i < 16; ++i) { CX0[i] = 0.f; CX1[i] = 0.f; CY0[i] = 0.f; CY1[i] = 0.f; }

            CX0 = __builtin_amdgcn_mfma_f32_32x32x16_bf16(xa0, whi[0][0], CX0, 0, 0, 0);
            CX1 = __builtin_amdgcn_mfma_f32_32x32x16_bf16(xa0, whi[1][0], CX1, 0, 0, 0);
            CY0 = __builtin_amdgcn_mfma_f32_32x32x16_bf16(ya0, whi[0][0], CY0, 0, 0, 0);
            CY1 = __builtin_amdgcn_mfma_f32_32x32x16_bf16(ya0, whi[1][0], CY1, 0, 0, 0);
            CX0 = __builtin_amdgcn_mfma_f32_32x32x16_bf16(xa0, wlo[0][0], CX0, 0, 0, 0);
            CX1 = __builtin_amdgcn_mfma_f32_32x32x16_bf16(xa0, wlo[1][0], CX1, 0, 0, 0);
            CY0 = __builtin_amdgcn_mfma_f32_32x32x16_bf16(ya0, wlo[0][0], CY0, 0, 0, 0);
            CY1 = __builtin_amdgcn_mfma_f32_32x32x16_bf16(ya0, wlo[1][0], CY1, 0, 0, 0);
            CX0 = __builtin_amdgcn_mfma_f32_32x32x16_bf16(xa1, whi[0][1], CX0, 0, 0, 0);
            CX1 = __builtin_amdgcn_mfma_f32_32x32x16_bf16(xa1, whi[1][1], CX1, 0, 0, 0);
            CY0 = __builtin_amdgcn_mfma_f32_32x32x16_bf16(ya1, whi[0][1], CY0, 0, 0, 0);
            CY1 = __builtin_amdgcn_mfma_f32_32x32x16_bf16(ya1, whi[1][1], CY1, 0, 0, 0);
            CX0 = __builtin_amdgcn_mfma_f32_32x32x16_bf16(xa1, wlo[0][1], CX0, 0, 0, 0);
            CX1 = __builtin_amdgcn_mfma_f32_32x32x16_bf16(xa1, wlo[1][1], CX1, 0, 0, 0);
            CY0 = __builtin_amdgcn_mfma_f32_32x32x16_bf16(ya1, wlo[0][1], CY0, 0, 0, 0);
            CY1 = __builtin_amdgcn_mfma_f32_32x32x16_bf16(ya1, wlo[1][1], CY1, 0, 0, 0);
            CX0 = __builtin_amdgcn_mfma_f32_32x32x16_bf16(xa2, whi[0][2], CX0, 0, 0, 0);
            CX1 = __builtin_amdgcn_mfma_f32_32x32x16_bf16(xa2, whi[1][2], CX1, 0, 0, 0);
            CY0 = __builtin_amdgcn_mfma_f32_32x32x16_bf16(ya2, whi[0][2], CY0, 0, 0, 0);
            CY1 = __builtin_amdgcn_mfma_f32_32x32x16_bf16(ya2, whi[1][2], CY1, 0, 0, 0);
            CX0 = __builtin_amdgcn_mfma_f32_32x32x16_bf16(xa2, wlo[0][2], CX0, 0, 0, 0);
            CX1 = __builtin_amdgcn_mfma_f32_32x32x16_bf16(xa2, wlo[1][2], CX1, 0, 0, 0);
            CY0 = __builtin_amdgcn_mfma_f32_32x32x16_bf16(ya2, wlo[0][2], CY0, 0, 0, 0);
            CY1 = __builtin_amdgcn_mfma_f32_32x32x16_bf16(ya2, wlo[1][2], CY1, 0, 0, 0);

            stat16(CX0, negb0, mx0, c0A, c0B);
            stat16(CY0, negb0, mx0, c0A, c0B);
            stat16(CX1, negb1, mx1, c1A, c1B);
            stat16(CY1, negb1, mx1, c1A, c1B);
        }
    }

    int cnt0 = c0A + c0B, cnt1 = c1A + c1B;

    // ---- merge complementary row halves across the (L, L^32) lane pair ----
    mx0  = fmaxf(mx0, __shfl_xor(mx0, 32));
    mx1  = fmaxf(mx1, __shfl_xor(mx1, 32));
    cnt0 += __shfl_xor(cnt0, 32);
    cnt1 += __shfl_xor(cnt1, 32);

    if (lane < 32) {
        float2* ob = reinterpret_cast<float2*>(out + (size_t)b * (2 * N_KERNELS));
        ob[n0] = make_float2(mx0 - negb0, (float)cnt0 * (1.0f / 1024.0f));
        ob[n1] = make_float2(mx1 - negb1, (float)cnt1 * (1.0f / 1024.0f));
    }
}

__global__ __launch_bounds__(256, 2)
void rocket_main(const float* __restrict__ x, const float* __restrict__ wgt,
                 const float* __restrict__ bias, const int* __restrict__ list,
                 const int* __restrict__ sched, float* __restrict__ out) {
    __shared__ __align__(16) short xs[8 * PP_STRIDE];   // 61.5 KB
    int4 e = reinterpret_cast<const int4*>(sched)[blockIdx.x];
    if (e.w == 0) return;                                // dead chunk — uniform exit
    int b = blockIdx.y;
    int kc = e.x, ld2 = e.y, lstart = e.z, valid = e.w;
    switch (kc * 8 + ld2) {
        case 7*8+0:  body<7, 1 >(x, wgt, bias, list, lstart, valid, out, xs, b); break;
        case 7*8+1:  body<7, 2 >(x, wgt, bias, list, lstart, valid, out, xs, b); break;
        case 7*8+2:  body<7, 4 >(x, wgt, bias, list, lstart, valid, out, xs, b); break;
        case 7*8+3:  body<7, 8 >(x, wgt, bias, list, lstart, valid, out, xs, b); break;
        case 7*8+4:  body<7, 16>(x, wgt, bias, list, lstart, valid, out, xs, b); break;
        case 9*8+0:  body<9, 1 >(x, wgt, bias, list, lstart, valid, out, xs, b); break;
        case 9*8+1:  body<9, 2 >(x, wgt, bias, list, lstart, valid, out, xs, b); break;
        case 9*8+2:  body<9, 4 >(x, wgt, bias, list, lstart, valid, out, xs, b); break;
        case 9*8+3:  body<9, 8 >(x, wgt, bias, list, lstart, valid, out, xs, b); break;
        case 9*8+4:  body<9, 16>(x, wgt, bias, list, lstart, valid, out, xs, b); break;
        case 11*8+0: body<11,1 >(x, wgt, bias, list, lstart, valid, out, xs, b); break;
        case 11*8+1: body<11,2 >(x, wgt, bias, list, lstart, valid, out, xs, b); break;
        case 11*8+2: body<11,4 >(x, wgt, bias, list, lstart, valid, out, xs, b); break;
        case 11*8+3: body<11,8 >(x, wgt, bias, list, lstart, valid, out, xs, b); break;
        default:     body<11,16>(x, wgt, bias, list, lstart, valid, out, xs, b); break;
    }
}

extern "C" void kernel_launch(void* const* d_in, const int* in_sizes, int n_in,
                              void* d_out, int out_size, void* d_ws, size_t ws_size,
                              hipStream_t stream) {
    const float* x   = (const float*)d_in[0];
    const float* w   = (const float*)d_in[1];
    const float* b   = (const float*)d_in[2];
    float* out = (float*)d_out;

    int* wsi  = (int*)d_ws;
    int* karr = wsi;            // 10000
    int* darr = wsi + 10000;    // 10000
    int* list = wsi + 20000;    // 10000
    int* schd = wsi + 30000;    // NCHUNK*4 ints (16B aligned)

    hipLaunchKernelGGL(setup_kernel, dim3(1), dim3(256), 0, stream,
                       karr, darr, list, schd);
    hipLaunchKernelGGL(rocket_main,  dim3(NCHUNK, 64), dim3(256), 0, stream,
                       x, w, b, list, schd, out);
}

// Round 8
// 222.277 us; speedup vs baseline: 5.6102x; 1.1795x over previous
//
#include <hip/hip_runtime.h>
#include <stdint.h>

#define N_KERNELS 10000
#define NCHUNK 56            // >= sum_g ceil(size_g/256) worst case
#define RNG_STEPS 40         // 256 lanes * 40 next64 = 20480 u32 draws >= 20000
#define CH_ALLOC 1312        // shorts per (copy,channel); mult of 4 (8B align)
#define PP_STRIDE (3 * CH_ALLOC)
#define NPHASE 4

typedef unsigned __int128 u128;
typedef __attribute__((ext_vector_type(4)))  short short4v;
typedef __attribute__((ext_vector_type(8)))  short short8;
typedef __attribute__((ext_vector_type(16))) float floatx16;

// ---------------------------------------------------------------------------
// Setup: (1) numpy default_rng(0) -> PCG64 -> integers(0,3) x10000,
// integers(0,5) x10000 (verified R1-R7). (2) bucket by (k,d); chunk table
// sched[ci] = int4{ k, log2(d), list_start, valid } (valid==0 -> dead).
// ---------------------------------------------------------------------------
__global__ void setup_kernel(int* __restrict__ karr, int* __restrict__ darr,
                             int* __restrict__ list, int* __restrict__ sched) {
    const u128 MULT = (((u128)0x2360ED051FC65DA4ULL) << 64) | 0x4385DF649FCCF645ULL;
    const int tid = threadIdx.x;

    uint32_t hc = 0x43b0d7e5u;                    // INIT_A
    auto hashmix = [&hc](uint32_t v) -> uint32_t {
        v ^= hc; hc *= 0x931e8875u;               // MULT_A
        v *= hc; v ^= v >> 16; return v;
    };
    uint32_t pool[4];
    pool[0] = hashmix(0u);
    pool[1] = hashmix(0u);
    pool[2] = hashmix(0u);
    pool[3] = hashmix(0u);
    for (int s = 0; s < 4; s++)
        for (int dd = 0; dd < 4; dd++)
            if (s != dd) {
                uint32_t hv = hashmix(pool[s]);
                uint32_t rr = 0xca01f9ddu * pool[dd] - 0x4973f715u * hv;
                rr ^= rr >> 16;
                pool[dd] = rr;
            }
    uint32_t st[8];
    uint32_t hcb = 0x8b51f9ddu;                   // INIT_B
    for (int i = 0; i < 8; i++) {
        uint32_t dv = pool[i & 3];
        dv ^= hcb; hcb *= 0x58f38dedu;            // MULT_B
        dv *= hcb; dv ^= dv >> 16;
        st[i] = dv;
    }
    uint64_t w0 = (uint64_t)st[0] | ((uint64_t)st[1] << 32);
    uint64_t w1 = (uint64_t)st[2] | ((uint64_t)st[3] << 32);
    uint64_t w2 = (uint64_t)st[4] | ((uint64_t)st[5] << 32);
    uint64_t w3 = (uint64_t)st[6] | ((uint64_t)st[7] << 32);
    u128 initstate = (((u128)w0) << 64) | w1;
    u128 initseq   = (((u128)w2) << 64) | w3;

    u128 inc   = (initseq << 1) | 1;
    u128 state = 0;
    state = state * MULT + inc;
    state += initstate;
    state = state * MULT + inc;

    u128 Ae = 1, Ce = 0, Ab = MULT, Cb = inc;
    unsigned e = (unsigned)(tid * RNG_STEPS);
    while (e) {
        if (e & 1u) { Ae = Ab * Ae; Ce = Ab * Ce + Cb; }
        Cb = Ab * Cb + Cb;
        Ab = Ab * Ab;
        e >>= 1;
    }
    u128 s = Ae * state + Ce;

    int base = tid * (2 * RNG_STEPS);
    for (int t = 0; t < RNG_STEPS; t++) {
        s = s * MULT + inc;
        uint64_t hi = (uint64_t)(s >> 64), lo = (uint64_t)s;
        unsigned rot = (unsigned)(hi >> 58);
        uint64_t v = hi ^ lo;
        uint64_t o = (v >> rot) | (v << ((64u - rot) & 63u));
        uint32_t d0 = (uint32_t)o;
        uint32_t d1 = (uint32_t)(o >> 32);
        int i0 = base + 2 * t;
        if (i0 < 10000)       karr[i0] = (int)(((uint64_t)d0 * 3u) >> 32);
        else if (i0 < 20000)  darr[i0 - 10000] = (int)(((uint64_t)d0 * 5u) >> 32);
        int i1 = i0 + 1;
        if (i1 < 10000)       karr[i1] = (int)(((uint64_t)d1 * 3u) >> 32);
        else if (i1 < 20000)  darr[i1 - 10000] = (int)(((uint64_t)d1 * 5u) >> 32);
    }

    __syncthreads();   // karr/darr visible to the whole (single) block

    __shared__ int cnt[16], off[16], cur[16];
    if (tid < 16) cnt[tid] = 0;
    __syncthreads();
    for (int i = tid; i < N_KERNELS; i += 256)
        atomicAdd(&cnt[karr[i] * 5 + darr[i]], 1);
    __syncthreads();
    if (tid == 0) { int o = 0; for (int g = 0; g < 15; g++) { off[g] = o; o += cnt[g]; } }
    __syncthreads();
    if (tid < 16) cur[tid] = 0;
    __syncthreads();
    for (int i = tid; i < N_KERNELS; i += 256) {
        int g = karr[i] * 5 + darr[i];
        list[off[g] + atomicAdd(&cur[g], 1)] = i;
    }
    __syncthreads();
    if (tid == 0) {
        const int kv[3] = {7, 9, 11};
        int ci = 0;
        for (int g = 0; g < 15; g++) {
            int sz = cnt[g];
            for (int s2 = 0; s2 < sz; s2 += 256) {
                int4 e2;
                e2.x = kv[g / 5];
                e2.y = g % 5;
                e2.z = off[g] + s2;
                e2.w = (sz - s2 < 256) ? (sz - s2) : 256;
                reinterpret_cast<int4*>(sched)[ci++] = e2;
            }
        }
        for (; ci < NCHUNK; ci++) {
            int4 e2; e2.x = 0; e2.y = 0; e2.z = 0; e2.w = 0;
            reinterpret_cast<int4*>(sched)[ci] = e2;
        }
    }
}

// ---------------------------------------------------------------------------
// Main: bf16 MFMA Toeplitz GEMM (R6 coverage structure, verified correct).
// R8 perf changes: 4 phase-copies (31.5 KB LDS -> 4 blocks/CU) with A-frags
// as 2x 8B loads; no sub-phase unroll (fits 128-reg budget); C init to BIAS
// so epilogue is sign-bit count (2 indep VALU/elem) + v_max3 tree; max
// stored directly (= conv+bias as in reference).
// ---------------------------------------------------------------------------
__device__ __forceinline__ uint16_t f32_to_bf16(float v) {
    uint32_t u = __builtin_bit_cast(uint32_t, v);
    return (uint16_t)((u + 0x7FFFu + ((u >> 16) & 1u)) >> 16);
}

__device__ __forceinline__ void stat16(const floatx16& C,
                                       float& mx, int& nA, int& nB) {
    // max via v_max3-fusable triples (tree), then fold into running mx
    float g0 = fmaxf(fmaxf(C[0],  C[1]),  C[2]);
    float g1 = fmaxf(fmaxf(C[3],  C[4]),  C[5]);
    float g2 = fmaxf(fmaxf(C[6],  C[7]),  C[8]);
    float g3 = fmaxf(fmaxf(C[9],  C[10]), C[11]);
    float g4 = fmaxf(fmaxf(C[12], C[13]), C[14]);
    float h0 = fmaxf(fmaxf(g0, g1), g2);
    float h1 = fmaxf(fmaxf(g3, g4), C[15]);
    mx = fmaxf(mx, fmaxf(h0, h1));
    // negative-count via sign bit, two independent chains (no carry dep)
    #pragma unroll
    for (int i = 0; i < 16; i += 2) {
        nA += (int)(__builtin_bit_cast(uint32_t, C[i])     >> 31);
        nB += (int)(__builtin_bit_cast(uint32_t, C[i + 1]) >> 31);
    }
}

template <int K, int D>
__device__ __forceinline__ void body(const float* __restrict__ x,
                                     const float* __restrict__ wgt,
                                     const float* __restrict__ bias,
                                     const int* __restrict__ list,
                                     int lstart, int valid,
                                     float* __restrict__ out,
                                     short* __restrict__ xs,   // [4][3][CH_ALLOC]
                                     int b) {
    constexpr int H   = (K - 1) / 2;
    constexpr int Q   = 1024 / D;
    constexpr int S   = Q + 16;                    // residue slot stride (gap 16)
    constexpr int RS  = (D <= 4) ? 8 : (D == 8 ? 4 : 2);   // row stride (positions)
    constexpr int PH  = RS;                        // sub-phases per range
    constexpr int NRG = (D <= 4) ? 4 : D;          // ranges
    constexpr int RPERRES = (D <= 4) ? (4 / D) : 1;

    const int tid   = threadIdx.x;
    const int lane  = tid & 63;
    const int wave  = tid >> 6;
    const int jbase = (lane >> 5) * 8;             // k-half offset (0 or 8; ==0 mod 4)

    // ---- stage: write the 4 phase-copies of the padded bf16 signal --------
    // rep[pp][c][e] = sig_c[e+pp]; sig mem layout: [8 front | r*S + q | ...],
    // value at mempos m: y=m-8, r=y/S, q=y%S -> x[c, r+D*q] if r<D && q<Q else 0.
    for (int idx = tid; idx < 3 * (CH_ALLOC + NPHASE); idx += 256) {
        int c = idx / (CH_ALLOC + NPHASE);
        int P = idx - c * (CH_ALLOC + NPHASE);
        float v = 0.f;
        int y = P - 8;
        if (y >= 0) {
            int r = y / S;
            int q = y - r * S;
            if (r < D && q < Q) v = x[((size_t)b * 3 + c) * 1024 + r + D * q];
        }
        short hv = (short)f32_to_bf16(v);
        #pragma unroll
        for (int pp = 0; pp < NPHASE; ++pp) {
            int e = P - pp;
            if (e >= 0 && e < CH_ALLOC)
                xs[pp * PP_STRIDE + c * CH_ALLOC + e] = hv;
        }
    }

    // ---- per-lane B fragments (weights, hi/lo split), overlap staging -----
    int i0 = wave * 64 + (lane & 31);
    int i1 = i0 + 32;
    int n0 = list[lstart + (i0 < valid ? i0 : valid - 1)];
    int n1 = list[lstart + (i1 < valid ? i1 : valid - 1)];
    short8 whi[2][3], wlo[2][3];
    #pragma unroll
    for (int t2 = 0; t2 < 2; ++t2) {
        int n = t2 ? n1 : n0;
        #pragma unroll
        for (int c = 0; c < 3; ++c) {
            #pragma unroll
            for (int u = 0; u < 8; ++u) {
                int j = jbase + u;
                float wv = (j < 11) ? wgt[n * 33 + c * 11 + j] : 0.f;
                uint16_t h = f32_to_bf16(wv);
                float hf = __builtin_bit_cast(float, (uint32_t)h << 16);
                uint16_t l = f32_to_bf16(wv - hf);
                whi[t2][c][u] = (short)h;
                wlo[t2][c][u] = (short)l;
            }
        }
    }
    float bv0 = bias[n0], bv1 = bias[n1];

    __syncthreads();

    // ---- main loop: NRG ranges x PH sub-phases, no further barriers -------
    float mx0 = -3.402823466e38f, mx1 = -3.402823466e38f;
    int n0A = 0, n0B = 0, n1A = 0, n1B = 0;        // negative counts
    const int m31 = lane & 31;                     // A row / C-D column index

    #pragma unroll 1
    for (int ri = 0; ri < NRG; ++ri) {
        const int q0 = (D <= 4) ? (8 + (ri / RPERRES) * S + (ri % RPERRES) * 256)
                                : (8 + ri * S);
        #pragma unroll 1
        for (int p = 0; p < PH; ++p) {
            // row m covers position q0-8 + p + RS*m (all valid by construction)
            const int F  = q0 + p - H + RS * m31;  // window start (array index)
            const int pp = F & (NPHASE - 1);       // per-lane phase copy
            const int e  = (F & ~(NPHASE - 1)) + jbase;  // 8B-aligned elem offset
            const short* src = xs + pp * PP_STRIDE + e;
            short4v l0 = *reinterpret_cast<const short4v*>(src);
            short4v h0 = *reinterpret_cast<const short4v*>(src + 4);
            short4v l1 = *reinterpret_cast<const short4v*>(src + CH_ALLOC);
            short4v h1 = *reinterpret_cast<const short4v*>(src + CH_ALLOC + 4);
            short4v l2 = *reinterpret_cast<const short4v*>(src + 2 * CH_ALLOC);
            short4v h2 = *reinterpret_cast<const short4v*>(src + 2 * CH_ALLOC + 4);
            short8 a0 = __builtin_shufflevector(l0, h0, 0, 1, 2, 3, 4, 5, 6, 7);
            short8 a1 = __builtin_shufflevector(l1, h1, 0, 1, 2, 3, 4, 5, 6, 7);
            short8 a2 = __builtin_shufflevector(l2, h2, 0, 1, 2, 3, 4, 5, 6, 7);

            floatx16 C0, C1;
            #pragma unroll
            for (int i = 0; i < 16; ++i) { C0[i] = bv0; C1[i] = bv1; }
            C0 = __builtin_amdgcn_mfma_f32_32x32x16_bf16(a0, whi[0][0], C0, 0, 0, 0);
            C1 = __builtin_amdgcn_mfma_f32_32x32x16_bf16(a0, whi[1][0], C1, 0, 0, 0);
            C0 = __builtin_amdgcn_mfma_f32_32x32x16_bf16(a0, wlo[0][0], C0, 0, 0, 0);
            C1 = __builtin_amdgcn_mfma_f32_32x32x16_bf16(a0, wlo[1][0], C1, 0, 0, 0);
            C0 = __builtin_amdgcn_mfma_f32_32x32x16_bf16(a1, whi[0][1], C0, 0, 0, 0);
            C1 = __builtin_amdgcn_mfma_f32_32x32x16_bf16(a1, whi[1][1], C1, 0, 0, 0);
            C0 = __builtin_amdgcn_mfma_f32_32x32x16_bf16(a1, wlo[0][1], C0, 0, 0, 0);
            C1 = __builtin_amdgcn_mfma_f32_32x32x16_bf16(a1, wlo[1][1], C1, 0, 0, 0);
            C0 = __builtin_amdgcn_mfma_f32_32x32x16_bf16(a2, whi[0][2], C0, 0, 0, 0);
            C1 = __builtin_amdgcn_mfma_f32_32x32x16_bf16(a2, whi[1][2], C1, 0, 0, 0);
            C0 = __builtin_amdgcn_mfma_f32_32x32x16_bf16(a2, wlo[0][2], C0, 0, 0, 0);
            C1 = __builtin_amdgcn_mfma_f32_32x32x16_bf16(a2, wlo[1][2], C1, 0, 0, 0);

            stat16(C0, mx0, n0A, n0B);
            stat16(C1, mx1, n1A, n1B);
        }
    }

    int neg0 = n0A + n0B, neg1 = n1A + n1B;

    // ---- merge complementary row halves across the (L, L^32) lane pair ----
    mx0  = fmaxf(mx0, __shfl_xor(mx0, 32));
    mx1  = fmaxf(mx1, __shfl_xor(mx1, 32));
    neg0 += __shfl_xor(neg0, 32);
    neg1 += __shfl_xor(neg1, 32);

    if (lane < 32) {
        float2* ob = reinterpret_cast<float2*>(out + (size_t)b * (2 * N_KERNELS));
        ob[n0] = make_float2(mx0, (float)(1024 - neg0) * (1.0f / 1024.0f));
        ob[n1] = make_float2(mx1, (float)(1024 - neg1) * (1.0f / 1024.0f));
    }
}

__global__ __launch_bounds__(256, 4)
void rocket_main(const float* __restrict__ x, const float* __restrict__ wgt,
                 const float* __restrict__ bias, const int* __restrict__ list,
                 const int* __restrict__ sched, float* __restrict__ out) {
    __shared__ __align__(16) short xs[NPHASE * PP_STRIDE];   // 31.5 KB
    int4 e = reinterpret_cast<const int4*>(sched)[blockIdx.x];
    if (e.w == 0) return;                                // dead chunk — uniform exit
    int b = blockIdx.y;
    int kc = e.x, ld2 = e.y, lstart = e.z, valid = e.w;
    switch (kc * 8 + ld2) {
        case 7*8+0:  body<7, 1 >(x, wgt, bias, list, lstart, valid, out, xs, b); break;
        case 7*8+1:  body<7, 2 >(x, wgt, bias, list, lstart, valid, out, xs, b); break;
        case 7*8+2:  body<7, 4 >(x, wgt, bias, list, lstart, valid, out, xs, b); break;
        case 7*8+3:  body<7, 8 >(x, wgt, bias, list, lstart, valid, out, xs, b); break;
        case 7*8+4:  body<7, 16>(x, wgt, bias, list, lstart, valid, out, xs, b); break;
        case 9*8+0:  body<9, 1 >(x, wgt, bias, list, lstart, valid, out, xs, b); break;
        case 9*8+1:  body<9, 2 >(x, wgt, bias, list, lstart, valid, out, xs, b); break;
        case 9*8+2:  body<9, 4 >(x, wgt, bias, list, lstart, valid, out, xs, b); break;
        case 9*8+3:  body<9, 8 >(x, wgt, bias, list, lstart, valid, out, xs, b); break;
        case 9*8+4:  body<9, 16>(x, wgt, bias, list, lstart, valid, out, xs, b); break;
        case 11*8+0: body<11,1 >(x, wgt, bias, list, lstart, valid, out, xs, b); break;
        case 11*8+1: body<11,2 >(x, wgt, bias, list, lstart, valid, out, xs, b); break;
        case 11*8+2: body<11,4 >(x, wgt, bias, list, lstart, valid, out, xs, b); break;
        case 11*8+3: body<11,8 >(x, wgt, bias, list, lstart, valid, out, xs, b); break;
        default:     body<11,16>(x, wgt, bias, list, lstart, valid, out, xs, b); break;
    }
}

extern "C" void kernel_launch(void* const* d_in, const int* in_sizes, int n_in,
                              void* d_out, int out_size, void* d_ws, size_t ws_size,
                              hipStream_t stream) {
    const float* x   = (const float*)d_in[0];
    const float* w   = (const float*)d_in[1];
    const float* b   = (const float*)d_in[2];
    float* out = (float*)d_out;

    int* wsi  = (int*)d_ws;
    int* karr = wsi;            // 10000
    int* darr = wsi + 10000;    // 10000
    int* list = wsi + 20000;    // 10000
    int* schd = wsi + 30000;    // NCHUNK*4 ints (16B aligned)

    hipLaunchKernelGGL(setup_kernel, dim3(1), dim3(256), 0, stream,
                       karr, darr, list, schd);
    hipLaunchKernelGGL(rocket_main,  dim3(NCHUNK, 64), dim3(256), 0, stream,
                       x, w, b, list, schd, out);
}